// Round 1
// baseline (1512.131 us; speedup 1.0000x reference)
//
#include <hip/hip_runtime.h>
#include <hip/hip_bf16.h>
#include <math.h>

#define NB 16384      // tokens
#define DD 2048       // hidden dim
#define NE 8          // experts
#define TM 128
#define TN 128
#define BK 64
#define MAXMT (2 * NB / TM + NE)   // 264 worst-case M-tiles across experts

typedef float f32x4 __attribute__((ext_vector_type(4)));
typedef short bf16x8 __attribute__((ext_vector_type(8)));

__device__ __forceinline__ short f2bf(float f) {
  union { float f; unsigned u; } v; v.f = f;
  unsigned r = (v.u + 0x7FFFu + ((v.u >> 16) & 1u)) >> 16;  // RNE
  return (short)r;
}

__device__ __forceinline__ void gload16(const void* g, void* l) {
  __builtin_amdgcn_global_load_lds((const __attribute__((address_space(1))) void*)g,
                                   (__attribute__((address_space(3))) void*)l,
                                   16, 0, 0);
}

// ---- x (fp32) -> bf16, 8 elems/thread ----
__global__ void conv_x(const float* __restrict__ x, short* __restrict__ xb) {
  size_t i = ((size_t)blockIdx.x * 256 + threadIdx.x) * 8;
  f32x4 a = *(const f32x4*)(x + i);
  f32x4 b = *(const f32x4*)(x + i + 4);
  bf16x8 o;
  o[0] = f2bf(a[0]); o[1] = f2bf(a[1]); o[2] = f2bf(a[2]); o[3] = f2bf(a[3]);
  o[4] = f2bf(b[0]); o[5] = f2bf(b[1]); o[6] = f2bf(b[2]); o[7] = f2bf(b[3]);
  *(bf16x8*)(xb + i) = o;
}

// ---- expert_w (E,D,D fp32, [d][f]) -> bf16 transposed Wt[e][f][d] ----
__global__ void conv_wT(const float* __restrict__ w, short* __restrict__ wt) {
  __shared__ float tile[64][68];
  int bid = blockIdx.x;
  int e = bid >> 10;            // 32*32 tiles per expert
  int tt = bid & 1023;
  int d0 = (tt >> 5) << 6;
  int f0 = (tt & 31) << 6;
  const float* we = w + (size_t)e * DD * DD;
  int t = threadIdx.x;
  int col = (t & 15) << 2;
#pragma unroll
  for (int p = 0; p < 4; ++p) {
    int dl = (t >> 4) + p * 16;
    f32x4 v = *(const f32x4*)(we + (size_t)(d0 + dl) * DD + f0 + col);
    *(f32x4*)&tile[dl][col] = v;
  }
  __syncthreads();
  int fl = t >> 2;
  int ds = (t & 3) << 4;
  short tmp[16];
#pragma unroll
  for (int j = 0; j < 16; ++j) tmp[j] = f2bf(tile[ds + j][fl]);
  short* dst = wt + (size_t)e * DD * DD + (size_t)(f0 + fl) * DD + d0 + ds;
  *(bf16x8*)dst = *(const bf16x8*)tmp;
  *(bf16x8*)(dst + 8) = *(const bf16x8*)(tmp + 8);
}

// ---- gate: logits (fp64 accum), top-2, softmax, histogram ----
__global__ void gate_topk(const float* __restrict__ x, const float* __restrict__ gw,
                          const float* __restrict__ gb, int* __restrict__ ridx,
                          float* __restrict__ rw, int* __restrict__ counts) {
  int wid = threadIdx.x >> 6;
  int lane = threadIdx.x & 63;
  int b = blockIdx.x * 4 + wid;
  const float* xr = x + (size_t)b * DD;
  double acc[8];
#pragma unroll
  for (int e = 0; e < 8; ++e) acc[e] = 0.0;
  for (int d = lane; d < DD; d += 64) {
    float xv = xr[d];
    f32x4 g0 = *(const f32x4*)(gw + d * 8);
    f32x4 g1 = *(const f32x4*)(gw + d * 8 + 4);
    double xd = (double)xv;
    acc[0] += xd * g0[0]; acc[1] += xd * g0[1];
    acc[2] += xd * g0[2]; acc[3] += xd * g0[3];
    acc[4] += xd * g1[0]; acc[5] += xd * g1[1];
    acc[6] += xd * g1[2]; acc[7] += xd * g1[3];
  }
#pragma unroll
  for (int off = 32; off > 0; off >>= 1) {
#pragma unroll
    for (int e = 0; e < 8; ++e) acc[e] += __shfl_down(acc[e], off);
  }
  if (lane == 0) {
    double l[8];
#pragma unroll
    for (int e = 0; e < 8; ++e) l[e] = acc[e] + (double)gb[e];
    int i0 = 0;
#pragma unroll
    for (int e = 1; e < 8; ++e) if (l[e] > l[i0]) i0 = e;
    int i1 = (i0 == 0) ? 1 : 0;
#pragma unroll
    for (int e = 0; e < 8; ++e) if (e != i0 && l[e] > l[i1]) i1 = e;
    double z = exp(l[i1] - l[i0]);              // <= 1
    float w0 = (float)(1.0 / (1.0 + z));
    float w1 = (float)(z / (1.0 + z));
    ridx[2 * b] = i0; ridx[2 * b + 1] = i1;
    rw[2 * b] = w0;   rw[2 * b + 1] = w1;
    atomicAdd(&counts[i0], 1);
    atomicAdd(&counts[i1], 1);
  }
}

__global__ void scan8(const int* __restrict__ counts, int* __restrict__ offs) {
  if (threadIdx.x == 0 && blockIdx.x == 0) {
    int o = 0;
    for (int e = 0; e < NE; ++e) { offs[e] = o; o += counts[e]; }
  }
}

__global__ void scatter_tok(const int* __restrict__ ridx, const float* __restrict__ rw,
                            const int* __restrict__ offs, int* __restrict__ cursors,
                            int* __restrict__ lists, float* __restrict__ elw) {
  int t = blockIdx.x * 256 + threadIdx.x;
#pragma unroll
  for (int k = 0; k < 2; ++k) {
    int e = ridx[2 * t + k];
    int pos = atomicAdd(&cursors[e], 1);
    int idx = offs[e] + pos;
    lists[idx] = t;
    elw[idx] = rw[2 * t + k];
  }
}

// ---- grouped GEMM: per expert, gathered tokens (M) x Wt (N=D), K=D ----
__global__ __launch_bounds__(256)
void moe_gemm(const short* __restrict__ xb, const short* __restrict__ wt,
              const float* __restrict__ eb, const int* __restrict__ counts,
              const int* __restrict__ offs, const int* __restrict__ lists,
              const float* __restrict__ elw, float* __restrict__ out) {
  __shared__ short As[TM * BK];   // [m][k] 128x64 bf16
  __shared__ short Bs[TN * BK];   // [n][k] 128x64 bf16 (Wt rows)

  int mt = blockIdx.x;
  int e = 0, cnt = 0;
  for (; e < NE; ++e) {
    cnt = counts[e];
    int te = (cnt + TM - 1) >> 7;
    if (mt < te) break;
    mt -= te;
  }
  if (e >= NE) return;

  int m0 = mt * TM;
  int n0 = blockIdx.y * TN;
  int off_e = offs[e];
  int tid = threadIdx.x;
  int lane = tid & 63, wid = tid >> 6;
  int wr = wid >> 1, wc = wid & 1;

  // staging coords: linear LDS byte offset = p*4096 + tid*16
  int srow = tid >> 3;            // row within tile (128B rows)
  int scol = (tid & 7) << 3;      // short offset within row
  const short* asrc[4];
  const short* bsrc[4];
#pragma unroll
  for (int p = 0; p < 4; ++p) {
    int r = srow + p * 32;
    int gr = m0 + r;
    int tok = lists[off_e + ((gr < cnt) ? gr : 0)];   // safe pad row
    asrc[p] = xb + (size_t)tok * DD + scol;
    bsrc[p] = wt + ((size_t)e * DD + (size_t)(n0 + r)) * DD + scol;
  }
  int ldsbase = wid * 512;        // shorts: 1024B per wave per pass

  f32x4 acc[4][4];
#pragma unroll
  for (int i = 0; i < 4; ++i)
#pragma unroll
    for (int j = 0; j < 4; ++j) acc[i][j] = (f32x4){0.f, 0.f, 0.f, 0.f};

  int lrow = lane & 15;
  int lk = (lane >> 4) << 3;

  for (int k0 = 0; k0 < DD; k0 += BK) {
#pragma unroll
    for (int p = 0; p < 4; ++p) {
      gload16(asrc[p] + k0, &As[p * 2048 + ldsbase]);
      gload16(bsrc[p] + k0, &Bs[p * 2048 + ldsbase]);
    }
    __syncthreads();
#pragma unroll
    for (int kk = 0; kk < 2; ++kk) {
      bf16x8 af[4], bfr[4];
#pragma unroll
      for (int i = 0; i < 4; ++i)
        af[i] = *(const bf16x8*)&As[(wr * 64 + i * 16 + lrow) * BK + kk * 32 + lk];
#pragma unroll
      for (int j = 0; j < 4; ++j)
        bfr[j] = *(const bf16x8*)&Bs[(wc * 64 + j * 16 + lrow) * BK + kk * 32 + lk];
#pragma unroll
      for (int i = 0; i < 4; ++i)
#pragma unroll
        for (int j = 0; j < 4; ++j)
          acc[i][j] = __builtin_amdgcn_mfma_f32_16x16x32_bf16(af[i], bfr[j], acc[i][j], 0, 0, 0);
    }
    __syncthreads();
  }

  // epilogue: bias + relu + gate-weight, scatter-add to out rows
  int r0 = (lane >> 4) << 2;
#pragma unroll
  for (int i = 0; i < 4; ++i) {
    int mloc = wr * 64 + i * 16 + r0;
#pragma unroll
    for (int r = 0; r < 4; ++r) {
      int gr = m0 + mloc + r;
      if (gr >= cnt) continue;
      int tok = lists[off_e + gr];
      float wgt = elw[off_e + gr];
      float* orow = out + (size_t)tok * DD;
#pragma unroll
      for (int j = 0; j < 4; ++j) {
        int n = n0 + wc * 64 + j * 16 + lrow;
        float v = acc[i][j][r] + eb[e * DD + n];
        v = fmaxf(v, 0.f) * wgt;
        atomicAdd(orow + n, v);
      }
    }
  }
}

extern "C" void kernel_launch(void* const* d_in, const int* in_sizes, int n_in,
                              void* d_out, int out_size, void* d_ws, size_t ws_size,
                              hipStream_t stream) {
  const float* x   = (const float*)d_in[0];
  const float* ewt = (const float*)d_in[1];
  const float* eb  = (const float*)d_in[2];
  const float* gw  = (const float*)d_in[3];
  const float* gb  = (const float*)d_in[4];
  float* out = (float*)d_out;

  char* ws = (char*)d_ws;
  short* xb      = (short*)(ws);                     // 67108864 B
  short* wt      = (short*)(ws + 67108864);          // 67108864 B
  int*   ridx    = (int*)  (ws + 134217728);         // 131072 B
  float* rw      = (float*)(ws + 134348800);         // 131072 B
  int*   lists   = (int*)  (ws + 134479872);         // 131072 B
  float* elw     = (float*)(ws + 134610944);         // 131072 B
  int*   counts  = (int*)  (ws + 134742016);         // 32 B
  int*   cursors = (int*)  (ws + 134742048);         // 32 B
  int*   offs    = (int*)  (ws + 134742080);         // 32 B

  hipMemsetAsync(counts, 0, 64, stream);             // counts + cursors
  hipMemsetAsync(out, 0, (size_t)NB * DD * 4, stream);

  conv_x<<<(NB * DD / 8) / 256, 256, 0, stream>>>(x, xb);
  conv_wT<<<NE * 32 * 32, 256, 0, stream>>>(ewt, wt);
  gate_topk<<<NB / 4, 256, 0, stream>>>(x, gw, gb, ridx, rw, counts);
  scan8<<<1, 64, 0, stream>>>(counts, offs);
  scatter_tok<<<NB / 256, 256, 0, stream>>>(ridx, rw, offs, cursors, lists, elw);
  moe_gemm<<<dim3(MAXMT, DD / TN), 256, 0, stream>>>(xb, wt, eb, counts, offs, lists, elw, out);
}

// Round 2
// 645.512 us; speedup vs baseline: 2.3425x; 2.3425x over previous
//
#include <hip/hip_runtime.h>
#include <hip/hip_bf16.h>
#include <math.h>

#define NB 16384      // tokens
#define DD 2048       // hidden dim
#define NE 8          // experts
#define TM 128
#define TN 128
#define BK 64
#define NT_TILES (DD / TN)                 // 16
#define MT_PER_PASS (NB / TM + NE)         // 136 worst-case M-tiles per pass
#define GEMM_GRID (MT_PER_PASS * NT_TILES) // 2176
#define BPX (GEMM_GRID / 8)                // 272 blocks per XCD chunk

typedef float f32x4 __attribute__((ext_vector_type(4)));
typedef short bf16x8 __attribute__((ext_vector_type(8)));

__device__ __forceinline__ short f2bf(float f) {
  union { float f; unsigned u; } v; v.f = f;
  unsigned r = (v.u + 0x7FFFu + ((v.u >> 16) & 1u)) >> 16;  // RNE
  return (short)r;
}

__device__ __forceinline__ void gload16(const void* g, void* l) {
  __builtin_amdgcn_global_load_lds((const __attribute__((address_space(1))) void*)g,
                                   (__attribute__((address_space(3))) void*)l,
                                   16, 0, 0);
}

// ---- x (fp32) -> bf16, 8 elems/thread ----
__global__ void conv_x(const float* __restrict__ x, short* __restrict__ xb) {
  size_t i = ((size_t)blockIdx.x * 256 + threadIdx.x) * 8;
  f32x4 a = *(const f32x4*)(x + i);
  f32x4 b = *(const f32x4*)(x + i + 4);
  bf16x8 o;
  o[0] = f2bf(a[0]); o[1] = f2bf(a[1]); o[2] = f2bf(a[2]); o[3] = f2bf(a[3]);
  o[4] = f2bf(b[0]); o[5] = f2bf(b[1]); o[6] = f2bf(b[2]); o[7] = f2bf(b[3]);
  *(bf16x8*)(xb + i) = o;
}

// ---- expert_w (E,D,D fp32, [d][f]) -> bf16 transposed Wt[e][f][d] ----
__global__ void conv_wT(const float* __restrict__ w, short* __restrict__ wt) {
  __shared__ float tile[64][68];
  int bid = blockIdx.x;
  int e = bid >> 10;            // 32*32 tiles per expert
  int tt = bid & 1023;
  int d0 = (tt >> 5) << 6;
  int f0 = (tt & 31) << 6;
  const float* we = w + (size_t)e * DD * DD;
  int t = threadIdx.x;
  int col = (t & 15) << 2;
#pragma unroll
  for (int p = 0; p < 4; ++p) {
    int dl = (t >> 4) + p * 16;
    f32x4 v = *(const f32x4*)(we + (size_t)(d0 + dl) * DD + f0 + col);
    *(f32x4*)&tile[dl][col] = v;
  }
  __syncthreads();
  int fl = t >> 2;
  int ds = (t & 3) << 4;
  short tmp[16];
#pragma unroll
  for (int j = 0; j < 16; ++j) tmp[j] = f2bf(tile[ds + j][fl]);
  short* dst = wt + (size_t)e * DD * DD + (size_t)(f0 + fl) * DD + d0 + ds;
  *(bf16x8*)dst = *(const bf16x8*)tmp;
  *(bf16x8*)(dst + 8) = *(const bf16x8*)(tmp + 8);
}

// ---- gate: logits (fp64 accum), top-2, softmax weights; NO atomics ----
__global__ void gate_topk(const float* __restrict__ x, const float* __restrict__ gw,
                          const float* __restrict__ gb, int* __restrict__ ridx,
                          float* __restrict__ rw) {
  int wid = threadIdx.x >> 6;
  int lane = threadIdx.x & 63;
  int b = blockIdx.x * 4 + wid;
  const float* xr = x + (size_t)b * DD;
  double acc[8];
#pragma unroll
  for (int e = 0; e < 8; ++e) acc[e] = 0.0;
  for (int d = lane; d < DD; d += 64) {
    float xv = xr[d];
    f32x4 g0 = *(const f32x4*)(gw + d * 8);
    f32x4 g1 = *(const f32x4*)(gw + d * 8 + 4);
    double xd = (double)xv;
    acc[0] += xd * g0[0]; acc[1] += xd * g0[1];
    acc[2] += xd * g0[2]; acc[3] += xd * g0[3];
    acc[4] += xd * g1[0]; acc[5] += xd * g1[1];
    acc[6] += xd * g1[2]; acc[7] += xd * g1[3];
  }
#pragma unroll
  for (int off = 32; off > 0; off >>= 1) {
#pragma unroll
    for (int e = 0; e < 8; ++e) acc[e] += __shfl_down(acc[e], off);
  }
  if (lane == 0) {
    double l[8];
#pragma unroll
    for (int e = 0; e < 8; ++e) l[e] = acc[e] + (double)gb[e];
    int i0 = 0;
#pragma unroll
    for (int e = 1; e < 8; ++e) if (l[e] > l[i0]) i0 = e;
    int i1 = (i0 == 0) ? 1 : 0;
#pragma unroll
    for (int e = 0; e < 8; ++e) if (e != i0 && l[e] > l[i1]) i1 = e;
    double z = exp(l[i1] - l[i0]);              // <= 1
    float w0 = (float)(1.0 / (1.0 + z));
    float w1 = (float)(z / (1.0 + z));
    ridx[2 * b] = i0; ridx[2 * b + 1] = i1;
    rw[2 * b] = w0;   rw[2 * b + 1] = w1;
  }
}

// ---- per-block histogram over 16 (k,e) buckets; plain stores ----
__global__ void hist_tok(const int* __restrict__ ridx, int* __restrict__ partials) {
  __shared__ int h[16];
  int t = threadIdx.x;
  if (t < 16) h[t] = 0;
  __syncthreads();
  int t0 = blockIdx.x * 512;
  for (int i = t; i < 512; i += 256) {
    int tok = t0 + i;
    atomicAdd(&h[ridx[2 * tok]], 1);
    atomicAdd(&h[8 + ridx[2 * tok + 1]], 1);
  }
  __syncthreads();
  if (t < 16) partials[blockIdx.x * 16 + t] = h[t];
}

// ---- tiny scan: bucket totals, per-pass expert offsets, per-block bases ----
__global__ void scan_small(const int* __restrict__ partials, int* __restrict__ base,
                           int* __restrict__ cnts, int* __restrict__ offs) {
  __shared__ int c[16], o[16];
  int j = threadIdx.x;
  if (j < 16) {
    int s = 0;
    for (int b = 0; b < 32; ++b) s += partials[b * 16 + j];
    c[j] = s; cnts[j] = s;
  }
  __syncthreads();
  if (j < 2) {
    int a = 0;
    for (int e = 0; e < 8; ++e) { o[j * 8 + e] = a; a += c[j * 8 + e]; }
  }
  __syncthreads();
  if (j < 16) {
    int r = o[j];
    offs[j] = o[j];
    for (int b = 0; b < 32; ++b) { base[b * 16 + j] = r; r += partials[b * 16 + j]; }
  }
}

// ---- scatter tokens into per-(k,expert) lists; LDS-rank, no global atomics ----
__global__ void scatter_tok(const int* __restrict__ ridx, const float* __restrict__ rw,
                            const int* __restrict__ base,
                            int* __restrict__ lists0, float* __restrict__ elw0,
                            int* __restrict__ lists1, float* __restrict__ elw1) {
  __shared__ int h[16];
  int t = threadIdx.x;
  if (t < 16) h[t] = 0;
  __syncthreads();
  int t0 = blockIdx.x * 512;
  const int* bb = base + blockIdx.x * 16;
  for (int i = t; i < 512; i += 256) {
    int tok = t0 + i;
    int e0 = ridx[2 * tok], e1 = ridx[2 * tok + 1];
    int r0 = atomicAdd(&h[e0], 1);
    int r1 = atomicAdd(&h[8 + e1], 1);
    int p0 = bb[e0] + r0;
    int p1 = bb[8 + e1] + r1;
    lists0[p0] = tok; elw0[p0] = rw[2 * tok];
    lists1[p1] = tok; elw1[p1] = rw[2 * tok + 1];
  }
}

// ---- grouped GEMM, one routing pass (k-slot). ADD=0: store; ADD=1: out += ----
template <int ADD>
__global__ __launch_bounds__(256)
void moe_gemm(const short* __restrict__ xb, const short* __restrict__ wt,
              const float* __restrict__ eb, const int* __restrict__ cnts,
              const int* __restrict__ offs, const int* __restrict__ lists,
              const float* __restrict__ elw, float* __restrict__ out) {
  __shared__ short As[TM * BK];   // [m][k] 128x64 bf16, XOR-swizzled storage
  __shared__ short Bs[TN * BK];

  // XCD-chunked bijective swizzle (GEMM_GRID % 8 == 0)
  int bid = blockIdx.x;
  int swz = (bid & 7) * BPX + (bid >> 3);
  int mt = swz % MT_PER_PASS;
  int nt = swz / MT_PER_PASS;

  int e = 0, cnt = 0;
  for (; e < NE; ++e) {
    cnt = cnts[e];
    int te = (cnt + TM - 1) >> 7;
    if (mt < te) break;
    mt -= te;
  }
  if (e >= NE) return;

  int m0 = mt * TM;
  int n0 = nt * TN;
  int off_e = offs[e];
  int tid = threadIdx.x;
  int lane = tid & 63, wid = tid >> 6;
  int wr = wid >> 1, wc = wid & 1;

  // staging: linear LDS dest (wave base + lane*16), inverse-swizzled source col.
  // dest row = p*32 + (tid>>3); logical col shorts = ((tid&7) ^ (row&7)) << 3
  int srow = tid >> 3;
  int scol = (((tid & 7) ^ (srow & 7)) << 3);
  const short* asrc[4];
  const short* bsrc[4];
#pragma unroll
  for (int p = 0; p < 4; ++p) {
    int r = srow + p * 32;
    int gr = m0 + r;
    int tok = lists[off_e + ((gr < cnt) ? gr : (cnt - 1))];   // safe pad row
    asrc[p] = xb + (size_t)tok * DD + scol;
    bsrc[p] = wt + ((size_t)e * DD + (size_t)(n0 + r)) * DD + scol;
  }
  int ldsbase = wid * 512;        // shorts

  f32x4 acc[4][4];
#pragma unroll
  for (int i = 0; i < 4; ++i)
#pragma unroll
    for (int j = 0; j < 4; ++j) acc[i][j] = (f32x4){0.f, 0.f, 0.f, 0.f};

  int lrow = lane & 15;
  int lk = (lane >> 4) << 3;       // shorts
  int x7 = (lrow & 7) << 3;        // XOR term (shorts), same for all frags

  for (int k0 = 0; k0 < DD; k0 += BK) {
#pragma unroll
    for (int p = 0; p < 4; ++p) {
      gload16(asrc[p] + k0, &As[p * 2048 + ldsbase]);
      gload16(bsrc[p] + k0, &Bs[p * 2048 + ldsbase]);
    }
    __syncthreads();
#pragma unroll
    for (int kk = 0; kk < 2; ++kk) {
      int pcol = ((kk * 32 + lk) ^ x7);
      bf16x8 af[4], bfr[4];
#pragma unroll
      for (int i = 0; i < 4; ++i)
        af[i] = *(const bf16x8*)&As[(wr * 64 + i * 16 + lrow) * BK + pcol];
#pragma unroll
      for (int j = 0; j < 4; ++j)
        bfr[j] = *(const bf16x8*)&Bs[(wc * 64 + j * 16 + lrow) * BK + pcol];
#pragma unroll
      for (int i = 0; i < 4; ++i)
#pragma unroll
        for (int j = 0; j < 4; ++j)
          acc[i][j] = __builtin_amdgcn_mfma_f32_16x16x32_bf16(af[i], bfr[j], acc[i][j], 0, 0, 0);
    }
    __syncthreads();
  }

  // epilogue: bias + relu + gate-weight; nontemporal store (or load-add-store)
  int r0 = (lane >> 4) << 2;
#pragma unroll
  for (int i = 0; i < 4; ++i) {
    int mloc = wr * 64 + i * 16 + r0;
#pragma unroll
    for (int r = 0; r < 4; ++r) {
      int gr = m0 + mloc + r;
      if (gr >= cnt) continue;
      int tok = lists[off_e + gr];
      float wgt = elw[off_e + gr];
      float* orow = out + (size_t)tok * DD;
#pragma unroll
      for (int j = 0; j < 4; ++j) {
        int n = n0 + wc * 64 + j * 16 + lrow;
        float v = acc[i][j][r] + eb[e * DD + n];
        v = fmaxf(v, 0.f) * wgt;
        if (ADD) v += __builtin_nontemporal_load(&orow[n]);
        __builtin_nontemporal_store(v, &orow[n]);
      }
    }
  }
}

extern "C" void kernel_launch(void* const* d_in, const int* in_sizes, int n_in,
                              void* d_out, int out_size, void* d_ws, size_t ws_size,
                              hipStream_t stream) {
  const float* x   = (const float*)d_in[0];
  const float* ewt = (const float*)d_in[1];
  const float* eb  = (const float*)d_in[2];
  const float* gw  = (const float*)d_in[3];
  const float* gb  = (const float*)d_in[4];
  float* out = (float*)d_out;

  char* ws = (char*)d_ws;
  short* xb      = (short*)(ws);                     // 67108864 B
  short* wt      = (short*)(ws + 67108864);          // 67108864 B
  int*   ridx    = (int*)  (ws + 134217728);         // 131072 B
  float* rw      = (float*)(ws + 134348800);         // 131072 B
  int*   lists0  = (int*)  (ws + 134479872);         // 65536 B
  float* elw0    = (float*)(ws + 134545408);         // 65536 B
  int*   lists1  = (int*)  (ws + 134610944);         // 65536 B
  float* elw1    = (float*)(ws + 134676480);         // 65536 B
  int*   partials= (int*)  (ws + 134742016);         // 2048 B
  int*   base    = (int*)  (ws + 134744064);         // 2048 B
  int*   cnts    = (int*)  (ws + 134746112);         // 64 B
  int*   offs    = (int*)  (ws + 134746176);         // 64 B

  conv_x<<<(NB * DD / 8) / 256, 256, 0, stream>>>(x, xb);
  conv_wT<<<NE * 32 * 32, 256, 0, stream>>>(ewt, wt);
  gate_topk<<<NB / 4, 256, 0, stream>>>(x, gw, gb, ridx, rw);
  hist_tok<<<32, 256, 0, stream>>>(ridx, partials);
  scan_small<<<1, 64, 0, stream>>>(partials, base, cnts, offs);
  scatter_tok<<<32, 256, 0, stream>>>(ridx, rw, base, lists0, elw0, lists1, elw1);
  moe_gemm<0><<<GEMM_GRID, 256, 0, stream>>>(xb, wt, eb, cnts,     offs,     lists0, elw0, out);
  moe_gemm<1><<<GEMM_GRID, 256, 0, stream>>>(xb, wt, eb, cnts + 8, offs + 8, lists1, elw1, out);
}